// Round 9
// baseline (5234.310 us; speedup 1.0000x reference)
//
#include <hip/hip_runtime.h>
#include <stdint.h>
#include <math.h>

// ---------------------------------------------------------------------------
// ODE-LSTM on MI355X -- R16: persistent RK4, attempt #3. f32 in/out.
// B=4096, OBS=256, H=1024, OUT=256, T=20 (19 RK4 steps).
//
// Persistent history: R10 (agent acquire fences -> L2 invalidate storm,
// 5 GB HBM refetch) and R13 (SC1 loads bypass L2 -> MALL latency-bound,
// 3.3 GB) both failed CROSS-XCD. R16 makes the panel dependency XCD-LOCAL
// by construction:
//   - each block reads its physical XCD via s_getreg(HW_REG_XCC_ID) and
//     claims a (bx, panel) slot from ITS OWN XCD's pool (8 panels/XCD,
//     16 blocks/panel). Producer and all consumers of a panel share one
//     L2 for ANY block->XCD mapping.
//   - producer: normal stores (write-through L1 -> L2), __syncthreads
//     (per-wave vmcnt(0) drain -> all stores in L2), relaxed agent
//     atomicAdd on cnt[panel]. NO fences, NO invalidates.
//   - consumer: poll cnt (atomic load, L1-bypassing), then A-loads with
//     SC0 (aux=1): bypass possibly-stale per-CU L1, hit the shared L2.
//   - W21T / u1b / Tb / Sb / own-tile P reads: block-private or read-only
//     across the phase boundary -> plain cached.
// Residual risk: XCD block-count imbalance -> unclaimed slot -> VISIBLE
// hang (slot>=128 guard returns; consumers spin). Never silent corruption.
// Math & op order identical to R12/R15 -> absmax must stay 0.00390625.
//
// Algebra (R11): u = h@W1+b1 carried, W21 = W2@W1, each stage ONE GEMM:
//   u2 = u1 + 0.5dt(t1_1@W21 + c2)         c2 = b2@W1
//   u3 = u1 + 0.5dt(t1_2@W21 + c2)
//   u4 = u1 +    dt(t1_3@W21 + c2)
//   u1'= u1 + (dt/6)(T@W21) + dt*c2        T = t1_1+2t1_2+2t1_3+t1_4
//   h_ode = h + S@W2 + (t19-t0)*b2         S = sum_s (dt_s/6) T_s
//
// ws (15 MiB): W21T[0,2) W2T[2,4) WiT[4,6.5) WoT[6.5,7) P0[7,15)
// d_out overlays (all dead before the final writes):
//   u1b bf16 [0,8) | Tb bf16 [8,16) | P1 bf16 [16,24) | Sb bf16 [24,32)
//   W1T bf16 [32,34) (init only) | c2 f32 [34M,+4K) | cnt/xcdCnt [+4K,+4K+288)
// final: out f32 bytes [0,4M) | h_new [4,20M) | c_new [20,36M)
// ---------------------------------------------------------------------------

typedef __attribute__((ext_vector_type(8))) short short8;
typedef __attribute__((ext_vector_type(4))) float float4v;

#define BK 64

__device__ __forceinline__ float bf2f(unsigned short u) {
  union { unsigned int i; float f; } x;
  x.i = ((unsigned int)u) << 16;
  return x.f;
}
__device__ __forceinline__ unsigned short f2bf(float f) {
  union { float f; unsigned int i; } x;
  x.f = f;
  unsigned int r = x.i + 0x7fffu + ((x.i >> 16) & 1u);  // RNE
  return (unsigned short)(r >> 16);
}
__device__ __forceinline__ void load16(const void* g, void* l) {
  __builtin_amdgcn_global_load_lds(
      (__attribute__((address_space(1))) void*)g,
      (__attribute__((address_space(3))) void*)l, 16, 0, 0);
}
// SC0 (aux=1): bypass the per-CU L1 (which may hold stale lines from a
// previous phase), serve from the XCD-shared L2. NOT SC1 (that bypasses L2
// too -- the R13 mistake).
__device__ __forceinline__ void load16_sc0(const void* g, void* l) {
  __builtin_amdgcn_global_load_lds(
      (__attribute__((address_space(1))) void*)g,
      (__attribute__((address_space(3))) void*)l, 16, 0, 1);
}
__device__ __forceinline__ short8 packbf8(const float* p) {
  float4v lo = *(const float4v*)p, hi = *(const float4v*)(p + 4);
  short8 s;
  s[0] = (short)f2bf(lo[0]); s[1] = (short)f2bf(lo[1]);
  s[2] = (short)f2bf(lo[2]); s[3] = (short)f2bf(lo[3]);
  s[4] = (short)f2bf(hi[0]); s[5] = (short)f2bf(hi[1]);
  s[6] = (short)f2bf(hi[2]); s[7] = (short)f2bf(hi[3]);
  return s;
}
__device__ __forceinline__ short8 pack2(float4v lo, float4v hi) {
  short8 s;
  s[0] = (short)f2bf(lo[0]); s[1] = (short)f2bf(lo[1]);
  s[2] = (short)f2bf(lo[2]); s[3] = (short)f2bf(lo[3]);
  s[4] = (short)f2bf(hi[0]); s[5] = (short)f2bf(hi[1]);
  s[6] = (short)f2bf(hi[2]); s[7] = (short)f2bf(hi[3]);
  return s;
}
// a - b for two wave-uniform floats; avoids the gfx950 two-SGPR-source
// V_ADD_F32 constant-bus miscompile (R11) by forcing a through a VGPR.
__device__ __forceinline__ float vsub_uniform(float a, float b) {
  float av;
  asm("v_mov_b32 %0, %1" : "=v"(av) : "s"(a));
  return av - b;
}

// ---------------------------------------------------------------------------
// Persistent RK4: 76 phases (19 steps x 4 stage-GEMMs), 64x64 tiles,
// grid 1024 = exact residency (4 blocks/CU), XCD-local panel semaphores.
// ---------------------------------------------------------------------------
__global__ __launch_bounds__(256, 4) void rk4_p2(
    const unsigned short* __restrict__ W21T,
    const float* __restrict__ tgrid,
    const float* __restrict__ c2,
    unsigned short* __restrict__ u1b,
    unsigned short* __restrict__ Tb,
    unsigned short* __restrict__ Sb,
    unsigned short* __restrict__ P0,
    unsigned short* __restrict__ P1,
    unsigned int* __restrict__ xcdCnt,
    unsigned int* __restrict__ cnt) {
  __shared__ short8 AsV[2][512];  // 64 rows x 8 swizzled chunks x 16B
  __shared__ short8 BsV[2][512];
  __shared__ unsigned int sClaim;

  const int t = threadIdx.x;
  // ---- XCD-local work claim ----
  if (t == 0) {
    unsigned int xcc;
    asm volatile("s_getreg_b32 %0, hwreg(HW_REG_XCC_ID)" : "=s"(xcc));
    const unsigned int x = xcc & 7u;
    const unsigned int s = __hip_atomic_fetch_add(
        xcdCnt + x, 1u, __ATOMIC_RELAXED, __HIP_MEMORY_SCOPE_AGENT);
    sClaim = (x << 8) | (s & 255u);
  }
  __syncthreads();
  const unsigned int claim = sClaim;
  const unsigned int slot = claim & 255u;
  if (slot >= 128u) return;  // imbalance: missing worker -> visible hang
  const int bx = (int)(slot & 15u);
  const int by = (int)(((claim >> 8) << 3) | (slot >> 4));

  const int mBase = by * 64, nBase = bx * 64;
  const int wave = t >> 6, lane = t & 63;
  const int wr = wave >> 1, wc = wave & 1;
  const int q = lane >> 4, m16 = lane & 15;
  const int r0 = t >> 3;               // staging row 0..31 (also row+32)
  const int kcl = (t & 7) ^ (r0 & 7);  // swizzled k-chunk ((r0+32)&7==r0&7)

  const size_t aOff = (size_t)(mBase + r0) * 1024 + kcl * 8;
  const unsigned short* const A0 = P0 + aOff;  // sub 0,2
  const unsigned short* const A1 = P1 + aOff;  // sub 1
  const unsigned short* const A3 = Tb + aOff;  // sub 3
  const unsigned short* const bG = W21T + (size_t)(nBase + r0) * 1024 + kcl * 8;

  const int colBase = nBase + wc * 32 + m16;
  const int rowBase = mBase + wr * 32 + q * 4;

#pragma unroll 1
  for (int p = 0; p < 76; ++p) {
    const int sub = p & 3, step = p >> 2;

    if (p > 0) {
      // Gate: all 16 panel blocks finished phase p-1. Producer stores are
      // in our shared L2 (write-through L1 + per-wave vmcnt drain at their
      // end-of-phase __syncthreads) before their cnt increment.
      if (t == 0) {
        const unsigned int tgt = 16u * (unsigned int)p;
        while (__hip_atomic_load(cnt + by, __ATOMIC_RELAXED,
                                 __HIP_MEMORY_SCOPE_AGENT) < tgt)
          __builtin_amdgcn_s_sleep(2);
      }
      __syncthreads();
    }

    const unsigned short* aU = (sub == 1) ? A1 : ((sub == 3) ? A3 : A0);

    float4v acc[2][2];
#pragma unroll
    for (int r = 0; r < 2; ++r)
#pragma unroll
      for (int c = 0; c < 2; ++c) acc[r][c] = (float4v){0.f, 0.f, 0.f, 0.f};

    auto stageT = [&](int buf, int k0) {
      load16_sc0(aU + k0, &AsV[buf][t]);                  // A: L1-bypass, L2-hit
      load16_sc0(aU + 32 * 1024 + k0, &AsV[buf][t + 256]);
      load16(bG + k0, &BsV[buf][t]);                      // B: plain cached
      load16(bG + 32 * 1024 + k0, &BsV[buf][t + 256]);
    };
    auto computeT = [&](int buf) {
#pragma unroll
      for (int kk = 0; kk < 2; ++kk) {
        const int kc = kk * 4 + q;
        short8 af[2], bfr[2];
#pragma unroll
        for (int r = 0; r < 2; ++r) {
          const int arow = wr * 32 + r * 16 + m16;
          af[r] = AsV[buf][arow * 8 + (kc ^ (arow & 7))];
          const int brow = wc * 32 + r * 16 + m16;
          bfr[r] = BsV[buf][brow * 8 + (kc ^ (brow & 7))];
        }
#pragma unroll
        for (int r = 0; r < 2; ++r)
#pragma unroll
          for (int c = 0; c < 2; ++c)
            acc[r][c] = __builtin_amdgcn_mfma_f32_16x16x32_bf16(
                af[r], bfr[c], acc[r][c], 0, 0, 0);
      }
    };

    // ---- 2-phase double-buffered K-loop, counted vmcnt(4) ----
    stageT(0, 0);
    int cur = 0;
#pragma unroll 1
    for (int k0 = BK; k0 < 1024; k0 += BK) {
      stageT(cur ^ 1, k0);
      asm volatile("s_waitcnt vmcnt(4)" ::: "memory");
      __builtin_amdgcn_sched_barrier(0);
      __builtin_amdgcn_s_barrier();
      __builtin_amdgcn_sched_barrier(0);
      computeT(cur);
      asm volatile("s_waitcnt lgkmcnt(0)" ::: "memory");
      __builtin_amdgcn_sched_barrier(0);
      __builtin_amdgcn_s_barrier();
      __builtin_amdgcn_sched_barrier(0);
      cur ^= 1;
    }
    asm volatile("s_waitcnt vmcnt(0)" ::: "memory");
    __builtin_amdgcn_sched_barrier(0);
    __builtin_amdgcn_s_barrier();
    __builtin_amdgcn_sched_barrier(0);
    computeT(cur);

    // ---- epilogue (identical math/order to R12 MODE 1..4) ----
    const float dtv = vsub_uniform(tgrid[step + 1], tgrid[step]);
#pragma unroll
    for (int r = 0; r < 2; ++r) {
#pragma unroll
      for (int c = 0; c < 2; ++c) {
        const int col = colBase + c * 16;
#pragma unroll
        for (int e = 0; e < 4; ++e) {
          const int row = rowBase + r * 16 + e;
          const size_t idx = (size_t)row * 1024 + col;
          const float v = acc[r][c][e];
          if (sub == 0) {        // G1
            const float u2 = bf2f(u1b[idx]) + 0.5f * dtv * (v + c2[col]);
            const float th = tanhf(u2);
            P1[idx] = f2bf(th);
            Tb[idx] = f2bf(bf2f(P0[idx]) + 2.f * th);   // P0[own] = t1_1
          } else if (sub == 1) { // G2
            const float u3 = bf2f(u1b[idx]) + 0.5f * dtv * (v + c2[col]);
            const float th = tanhf(u3);
            P0[idx] = f2bf(th);
            Tb[idx] = f2bf(bf2f(Tb[idx]) + 2.f * th);
          } else if (sub == 2) { // G3
            const float u4 = bf2f(u1b[idx]) + dtv * (v + c2[col]);
            Tb[idx] = f2bf(bf2f(Tb[idx]) + tanhf(u4));
          } else {               // G4
            const float u1n = bf2f(u1b[idx]) + (dtv * (1.f / 6.f)) * v + dtv * c2[col];
            u1b[idx] = f2bf(u1n);
            P0[idx] = f2bf(tanhf(u1n));
            const float sOld = (step == 0) ? 0.f : bf2f(Sb[idx]);
            Sb[idx] = f2bf(sOld + (dtv * (1.f / 6.f)) * bf2f(Tb[idx]));
          }
        }
      }
    }

    __syncthreads();  // per-wave vmcnt(0) drain: all stores now in our L2
    if (t == 0) {
      __hip_atomic_fetch_add(cnt + by, 1u, __ATOMIC_RELAXED,
                             __HIP_MEMORY_SCOPE_AGENT);
    }
  }
}

// ---------------------------------------------------------------------------
// C = A(MxK) * Bt(NxK bf16)^T, fused per-MODE epilogue. 64x64 tiles.
// MODE: 0 INIT (u1=h@W1+b1), 5 ZFIN (z=h+S@W2+(t19-t0)b2),
//       6 WT (W21T build), 7 OUT (out=h_new@Wo+bo).
// ---------------------------------------------------------------------------
template <int MODE, int ADT>
__global__ __launch_bounds__(256, 4) void gemm_ode(
    const void* Av, const unsigned short* __restrict__ Bt,
    int N, int K,
    const float* __restrict__ bias, const float* __restrict__ tgrid,
    int step, int first,
    unsigned short* __restrict__ u1b,
    unsigned short* __restrict__ Tb,
    unsigned short* __restrict__ Sb,
    unsigned short* __restrict__ t1dst,
    const void* aux,
    const float* __restrict__ c2,
    float* __restrict__ outF) {
  __shared__ short8 AsV[2][512];
  __shared__ short8 BsV[2][512];

  const int t = threadIdx.x;
  int bx = blockIdx.x, by = blockIdx.y;
  if (gridDim.x == 16 && gridDim.y == 64) {
    const int lin = bx + (by << 4);
    const int x = lin & 7, j = lin >> 3;
    bx = j & 15;
    by = (x << 3) | (j >> 4);
  }
  const int mBase = by * 64, nBase = bx * 64;
  const int wave = t >> 6, lane = t & 63;
  const int wr = wave >> 1, wc = wave & 1;
  const int q = lane >> 4, m16 = lane & 15;

  float4v acc[2][2];
#pragma unroll
  for (int r = 0; r < 2; ++r)
#pragma unroll
    for (int c = 0; c < 2; ++c) acc[r][c] = (float4v){0.f, 0.f, 0.f, 0.f};

  const int r0 = t >> 3;
  const int kcl = (t & 7) ^ (r0 & 7);
  const unsigned short* aU = (const unsigned short*)Av + (size_t)(mBase + r0) * K + kcl * 8;
  const float* aF = (const float*)Av + (size_t)(mBase + r0) * K + kcl * 8;
  const unsigned short* bG = Bt + (size_t)(nBase + r0) * K + kcl * 8;

  auto computeT = [&](int buf) {
#pragma unroll
    for (int kk = 0; kk < 2; ++kk) {
      const int kc = kk * 4 + q;
      short8 af[2], bfr[2];
#pragma unroll
      for (int r = 0; r < 2; ++r) {
        const int arow = wr * 32 + r * 16 + m16;
        af[r] = AsV[buf][arow * 8 + (kc ^ (arow & 7))];
        const int brow = wc * 32 + r * 16 + m16;
        bfr[r] = BsV[buf][brow * 8 + (kc ^ (brow & 7))];
      }
#pragma unroll
      for (int r = 0; r < 2; ++r)
#pragma unroll
        for (int c = 0; c < 2; ++c)
          acc[r][c] = __builtin_amdgcn_mfma_f32_16x16x32_bf16(af[r], bfr[c],
                                                              acc[r][c], 0, 0, 0);
    }
  };

  if constexpr (ADT == 1) {
    auto stageT = [&](int buf, int k0) {
      load16(aU + k0, &AsV[buf][t]);
      load16(aU + (size_t)32 * K + k0, &AsV[buf][t + 256]);
      load16(bG + k0, &BsV[buf][t]);
      load16(bG + (size_t)32 * K + k0, &BsV[buf][t + 256]);
    };
    stageT(0, 0);
    int cur = 0;
    for (int k0 = BK; k0 < K; k0 += BK) {
      stageT(cur ^ 1, k0);
      asm volatile("s_waitcnt vmcnt(4)" ::: "memory");
      __builtin_amdgcn_sched_barrier(0);
      __builtin_amdgcn_s_barrier();
      __builtin_amdgcn_sched_barrier(0);
      computeT(cur);
      asm volatile("s_waitcnt lgkmcnt(0)" ::: "memory");
      __builtin_amdgcn_sched_barrier(0);
      __builtin_amdgcn_s_barrier();
      __builtin_amdgcn_sched_barrier(0);
      cur ^= 1;
    }
    asm volatile("s_waitcnt vmcnt(0)" ::: "memory");
    __builtin_amdgcn_sched_barrier(0);
    __builtin_amdgcn_s_barrier();
    __builtin_amdgcn_sched_barrier(0);
    computeT(cur);
  } else {
    for (int k0 = 0; k0 < K; k0 += BK) {
      AsV[0][t] = packbf8(aF + k0);
      AsV[0][t + 256] = packbf8(aF + (size_t)32 * K + k0);
      load16(bG + k0, &BsV[0][t]);
      load16(bG + (size_t)32 * K + k0, &BsV[0][t + 256]);
      __builtin_amdgcn_s_waitcnt(0);
      __syncthreads();
      computeT(0);
      __syncthreads();
    }
  }

  float dtv = 0.f;
  if constexpr (MODE == 5) dtv = vsub_uniform(tgrid[step], tgrid[0]);

  const int colBase = nBase + wc * 32 + m16;
  const int rowBase = mBase + wr * 32 + q * 4;
#pragma unroll
  for (int r = 0; r < 2; ++r) {
#pragma unroll
    for (int c = 0; c < 2; ++c) {
      const int col = colBase + c * 16;
#pragma unroll
      for (int e = 0; e < 4; ++e) {
        const int row = rowBase + r * 16 + e;
        const size_t idx = (size_t)row * N + col;
        const float v = acc[r][c][e];
        if constexpr (MODE == 0) {
          const float u1 = v + bias[col];
          u1b[idx] = f2bf(u1);
          t1dst[idx] = f2bf(tanhf(u1));
        } else if constexpr (MODE == 5) {
          const float z = ((const float*)aux)[idx] + v + dtv * bias[col];
          t1dst[idx] = f2bf(z);
        } else if constexpr (MODE == 6) {
          t1dst[(size_t)col * 1024 + row] = f2bf(v);
        } else {  // MODE 7
          outF[idx] = v + bias[col];
        }
      }
    }
  }
}

// ---------------------------------------------------------------------------
// Fused gate + c_tilde dual GEMM, 64x64 tiles, 4 blocks/CU, pipelined (R15):
// A-side prefetched into registers one K-tile ahead, Bs double-buffered via
// global_load_lds; counted vmcnt(8). LDS 32 KB.
// ---------------------------------------------------------------------------
__global__ __launch_bounds__(256, 4) void gemm_fused(
    const float* __restrict__ x, const float* __restrict__ h,
    const unsigned short* __restrict__ zB,
    const unsigned short* __restrict__ WiT,  // 1024 x 1280 bf16
    const float* __restrict__ bi, const float* __restrict__ c_in,
    float* __restrict__ hnewF, float* __restrict__ cnewF) {
  __shared__ short8 AsG[512];
  __shared__ short8 AsC[512];
  __shared__ short8 Bs[2][512];

  const int t = threadIdx.x;
  int bx = blockIdx.x, by = blockIdx.y;
  {
    const int lin = bx + (by << 4);
    const int xc = lin & 7, j = lin >> 3;
    bx = j & 15;
    by = (xc << 3) | (j >> 4);
  }
  const int mBase = by * 64, nBase = bx * 64;
  const int wave = t >> 6, lane = t & 63;
  const int wr = wave >> 1, wc = wave & 1;
  const int q = lane >> 4, m16 = lane & 15;

  float4v accG[2][2], accC[2][2];
#pragma unroll
  for (int r = 0; r < 2; ++r)
#pragma unroll
    for (int c = 0; c < 2; ++c) {
      accG[r][c] = (float4v){0.f, 0.f, 0.f, 0.f};
      accC[r][c] = (float4v){0.f, 0.f, 0.f, 0.f};
    }

  const int r0 = t >> 3;
  const int kcl = (t & 7) ^ (r0 & 7);
  const int row0 = mBase + r0, row1 = row0 + 32;

  struct Regs { float4v a0, a1, a2, a3; short8 z0, z1; };
  Regs Ra, Rb;

  auto issueA = [&](int i, Regs& R) {
    const int k0 = i * 64;
    if (k0 < 256) {
      const float* g0 = x + (size_t)row0 * 256 + k0 + kcl * 8;
      const float* g1 = x + (size_t)row1 * 256 + k0 + kcl * 8;
      R.a0 = *(const float4v*)g0; R.a1 = *(const float4v*)(g0 + 4);
      R.a2 = *(const float4v*)g1; R.a3 = *(const float4v*)(g1 + 4);
      R.z0 = *(const short8*)(const void*)g0;  // dummy, keeps vmcnt uniform
      R.z1 = *(const short8*)(const void*)g1;
    } else {
      const size_t o0 = (size_t)row0 * 1024 + (k0 - 256) + kcl * 8;
      const size_t o1 = (size_t)row1 * 1024 + (k0 - 256) + kcl * 8;
      R.a0 = *(const float4v*)(h + o0); R.a1 = *(const float4v*)(h + o0 + 4);
      R.a2 = *(const float4v*)(h + o1); R.a3 = *(const float4v*)(h + o1 + 4);
      R.z0 = *(const short8*)(zB + o0);
      R.z1 = *(const short8*)(zB + o1);
    }
  };
  auto issueB = [&](int i, int buf) {
    const int k0 = i * 64;
    load16(WiT + (size_t)(nBase + r0) * 1280 + k0 + kcl * 8, &Bs[buf][t]);
    load16(WiT + (size_t)(nBase + r0 + 32) * 1280 + k0 + kcl * 8,
           &Bs[buf][t + 256]);
  };
  auto computeF = [&](int buf) {
#pragma unroll
    for (int kk = 0; kk < 2; ++kk) {
      const int kc = kk * 4 + q;
      short8 ag[2], ac[2], bfr[2];
#pragma unroll
      for (int r = 0; r < 2; ++r) {
        const int arow = wr * 32 + r * 16 + m16;
        ag[r] = AsG[arow * 8 + (kc ^ (arow & 7))];
        ac[r] = AsC[arow * 8 + (kc ^ (arow & 7))];
        const int brow = wc * 32 + r * 16 + m16;
        bfr[r] = Bs[buf][brow * 8 + (kc ^ (brow & 7))];
      }
#pragma unroll
      for (int r = 0; r < 2; ++r)
#pragma unroll
        for (int c = 0; c < 2; ++c) {
          accG[r][c] = __builtin_amdgcn_mfma_f32_16x16x32_bf16(ag[r], bfr[c],
                                                               accG[r][c], 0, 0, 0);
          accC[r][c] = __builtin_amdgcn_mfma_f32_16x16x32_bf16(ac[r], bfr[c],
                                                               accC[r][c], 0, 0, 0);
        }
    }
  };

  int buf = 0;
  auto stepF = [&](int i, Regs& Rc, Regs& Rn) {
    if (i + 1 < 20) {
      issueA(i + 1, Rn);
      issueB(i + 1, buf ^ 1);
      asm volatile("s_waitcnt vmcnt(8)" ::: "memory");  // tile i's 8 done
    } else {
      asm volatile("s_waitcnt vmcnt(0)" ::: "memory");
    }
    __builtin_amdgcn_sched_barrier(0);
    {
      const bool isX = (i * 64) < 256;
      const short8 s0 = pack2(Rc.a0, Rc.a1);
      const short8 s1 = pack2(Rc.a2, Rc.a3);
      AsG[t] = s0;
      AsG[t + 256] = s1;
      AsC[t] = isX ? s0 : Rc.z0;
      AsC[t + 256] = isX ? s1 : Rc.z1;
    }
    asm volatile("s_waitcnt lgkmcnt(0)" ::: "memory");
    __builtin_amdgcn_sched_barrier(0);
    __builtin_amdgcn_s_barrier();
    __builtin_amdgcn_sched_barrier(0);
    computeF(buf);
    asm volatile("s_waitcnt lgkmcnt(0)" ::: "memory");
    __builtin_amdgcn_sched_barrier(0);
    __builtin_amdgcn_s_barrier();  // all waves done reading As/Bs[buf]
    __builtin_amdgcn_sched_barrier(0);
    buf ^= 1;
  };

  issueA(0, Ra);
  issueB(0, 0);
#pragma unroll 1
  for (int ii = 0; ii < 20; ii += 2) {
    stepF(ii, Ra, Rb);
    stepF(ii + 1, Rb, Ra);
  }

  const int colBase = nBase + wc * 32 + m16;
  const int rowBase = mBase + wr * 32 + q * 4;
#pragma unroll
  for (int r = 0; r < 2; ++r) {
#pragma unroll
    for (int c = 0; c < 2; ++c) {
      const int col = colBase + c * 16;
      const float bv = bi[col];
#pragma unroll
      for (int e = 0; e < 4; ++e) {
        const int row = rowBase + r * 16 + e;
        const size_t idx = (size_t)row * 1024 + col;
        const float g = 1.f / (1.f + expf(-(accG[r][c][e] + bv)));
        const float ct = 1.f / (1.f + expf(-(accC[r][c][e] + bv)));
        const float cn = g * (c_in[idx] + ct);
        const float hn = g * tanhf(cn);
        hnewF[idx] = hn;
        cnewF[idx] = cn;
      }
    }
  }
}

// out[c][r] = bf16(in[r][c]); in f32 RxC. block (32,8), grid (C/32, R/32).
__global__ __launch_bounds__(256) void transpose_f32_bf16(
    const float* __restrict__ in, unsigned short* __restrict__ out,
    int R, int C) {
  __shared__ float tile[32][33];
  const int c0 = blockIdx.x * 32, r0 = blockIdx.y * 32;
  const int tx = threadIdx.x, ty = threadIdx.y;
#pragma unroll
  for (int i = 0; i < 32; i += 8)
    tile[ty + i][tx] = in[(size_t)(r0 + ty + i) * C + c0 + tx];
  __syncthreads();
#pragma unroll
  for (int i = 0; i < 32; i += 8)
    out[(size_t)(c0 + ty + i) * R + r0 + tx] = f2bf(tile[tx][ty + i]);
}

// c2[n] = sum_k b2[k]*W1[k,n]; also zero the semaphores/claim counters.
__global__ __launch_bounds__(256) void c2_gemv(
    const float* __restrict__ b2, const float* __restrict__ W1,
    float* __restrict__ c2v, unsigned int* __restrict__ sem) {
  if (blockIdx.x == 0 && threadIdx.x < 72) sem[threadIdx.x] = 0u;  // cnt[64]+xcd[8]
  const int n = blockIdx.x * 256 + threadIdx.x;
  float a = 0.f;
  for (int k = 0; k < 1024; ++k) a += b2[k] * W1[(size_t)k * 1024 + n];
  c2v[n] = a;
}

extern "C" void kernel_launch(void* const* d_in, const int* in_sizes, int n_in,
                              void* d_out, int out_size, void* d_ws, size_t ws_size,
                              hipStream_t stream) {
  const float* x  = (const float*)d_in[0];   // 4096x256
  const float* h  = (const float*)d_in[1];   // 4096x1024
  const float* c  = (const float*)d_in[2];   // 4096x1024
  const float* t  = (const float*)d_in[3];   // 20
  const float* Wi = (const float*)d_in[4];   // 1280x1024
  const float* bi = (const float*)d_in[5];   // 1024
  const float* Wo = (const float*)d_in[6];   // 1024x256
  const float* bo = (const float*)d_in[7];   // 256
  const float* W1 = (const float*)d_in[8];   // 1024x1024
  const float* b1 = (const float*)d_in[9];   // 1024
  const float* W2 = (const float*)d_in[10];  // 1024x1024
  const float* b2 = (const float*)d_in[11];  // 1024

  const size_t MB = 1ull << 20;
  char* ws = (char*)d_ws;
  unsigned short* W21T = (unsigned short*)(ws);                      // [0,2M)
  unsigned short* W2T  = (unsigned short*)(ws + 2 * MB);             // [2,4M)
  unsigned short* WiT  = (unsigned short*)(ws + 4 * MB);             // [4,6.5M)
  unsigned short* WoT  = (unsigned short*)(ws + 6 * MB + 512 * 1024);// [6.5,7M)
  unsigned short* P0   = (unsigned short*)(ws + 7 * MB);             // [7,15M)

  // d_out overlays (all dead before the final output writes)
  float*          outF  = (float*)d_out;
  float*          hnewF = outF + 1048576;                            // [4,20M)
  float*          cnewF = outF + 5242880;                            // [20,36M)
  unsigned short* u1b   = (unsigned short*)d_out;                    // [0,8M)
  unsigned short* Tb    = (unsigned short*)((char*)d_out + 8 * MB);  // [8,16M)
  unsigned short* P1    = (unsigned short*)((char*)d_out + 16 * MB); // [16,24M)
  unsigned short* Sb    = (unsigned short*)((char*)d_out + 24 * MB); // [24,32M)
  unsigned short* W1T   = (unsigned short*)((char*)d_out + 32 * MB); // [32,34M)
  float*          c2v   = (float*)((char*)d_out + 34 * MB);          // 4 KB
  unsigned int*   sem   = (unsigned int*)((char*)d_out + 34 * MB + 4096);
  unsigned int*   cnt   = sem;        // [0,64): panel semaphores
  unsigned int*   xcdC  = sem + 64;   // [64,72): per-XCD claim counters

  const dim3 tb(32, 8), blk(256), g(16, 64);

  // weight prep
  transpose_f32_bf16<<<dim3(32, 32), tb, 0, stream>>>(W1, W1T, 1024, 1024);
  transpose_f32_bf16<<<dim3(32, 32), tb, 0, stream>>>(W2, W2T, 1024, 1024);
  transpose_f32_bf16<<<dim3(32, 40), tb, 0, stream>>>(Wi, WiT, 1280, 1024);
  transpose_f32_bf16<<<dim3(8, 32),  tb, 0, stream>>>(Wo, WoT, 1024, 256);
  c2_gemv<<<4, blk, 0, stream>>>(b2, W1, c2v, sem);
  // W21T = (W2@W1)^T
  gemm_ode<6, 0><<<dim3(16, 16), blk, 0, stream>>>(
      W2, W1T, 1024, 1024, b1, t, 0, 0,
      nullptr, nullptr, nullptr, W21T, nullptr, nullptr, nullptr);
  // u1 = h@W1 + b1 ; t1_1 = tanh(u1) -> P0
  gemm_ode<0, 0><<<g, blk, 0, stream>>>(
      h, W1T, 1024, 1024, b1, t, 0, 0,
      u1b, nullptr, nullptr, P0, nullptr, nullptr, nullptr);

  // RK4: all 76 stage GEMMs in ONE persistent dispatch (XCD-local panels)
  rk4_p2<<<1024, blk, 0, stream>>>(W21T, t, c2v, u1b, Tb, Sb, P0, P1,
                                   xcdC, cnt);

  // z = h_ode = h + S@W2 + (t19-t0)*b2  -> bf16 into P0
  gemm_ode<5, 1><<<g, blk, 0, stream>>>(
      Sb, W2T, 1024, 1024, b2, t, 19, 0,
      nullptr, nullptr, nullptr, P0, h, nullptr, nullptr);

  // fused gate + c_tilde -> h_new, c_new (f32)
  gemm_fused<<<g, blk, 0, stream>>>(x, h, P0, WiT, bi, c, hnewF, cnewF);

  // out = h_new(f32) @ Wo + bo
  gemm_ode<7, 0><<<dim3(4, 64), blk, 0, stream>>>(
      hnewF, WoT, 256, 1024, bo, t, 0, 0,
      nullptr, nullptr, nullptr, nullptr, nullptr, nullptr, outF);
}

// Round 10
// 1646.618 us; speedup vs baseline: 3.1788x; 3.1788x over previous
//
#include <hip/hip_runtime.h>
#include <stdint.h>
#include <math.h>

// ---------------------------------------------------------------------------
// ODE-LSTM on MI355X -- R17 (final micro round). f32 in/out.
// B=4096, OBS=256, H=1024, OUT=256, T=20 (19 RK4 steps).
//
// Architecture locked: multi-dispatch (persistent failed 3x: R10 invalidate
// storm, R13 SC1/MALL, R16 SC0 L2-retention), 64x64 stage tiles at 4
// blocks/CU (R14's bigger tile regressed). R17 shavings:
//   1. prep_all: 4 transposes + c2 in ONE dispatch (c2: 4-way K-split,
//      deterministic LDS reduce).
//   2. ADT0 (f32-A) GEMMs pipelined: reg-staged A + dbuf B + vmcnt(6)
//      (INIT, W21T build, OUT -- was the drain loop).
//   3. Stage-GEMM epilogue preloads: last K-iter peeled; u1b/Tb/aux/c2
//      loads issued after tile-15 staging with vmcnt(4+P) counted wait
//      (P exact: 34 or 50 or 18 unmergeable scalar loads); they complete
//      under the last 2 MFMA blocks instead of stalling the epilogue.
//
// Algebra (R11): u = h@W1+b1 carried, W21 = W2@W1, each stage ONE GEMM:
//   u2 = u1 + 0.5dt(t1_1@W21 + c2)         c2 = b2@W1
//   u3 = u1 + 0.5dt(t1_2@W21 + c2)
//   u4 = u1 +    dt(t1_3@W21 + c2)
//   u1'= u1 + (dt/6)(T@W21) + dt*c2        T = t1_1+2t1_2+2t1_3+t1_4
//   h_ode = h + S@W2 + (t19-t0)*b2         S = sum_s (dt_s/6) T_s
//
// ws (15 MiB): W21T[0,2) W2T[2,4) WiT[4,6.5) WoT[6.5,7) P0[7,15)
// d_out overlays (all dead before the final writes):
//   u1b bf16 [0,8) | Tb bf16 [8,16) | P1 bf16 [16,24) | Sb bf16 [24,32)
//   W1T bf16 [32,34) (init only) | c2 f32 [34M,34M+4K)
// final: out f32 bytes [0,4M) | h_new [4,20M) | c_new [20,36M)
// ---------------------------------------------------------------------------

typedef __attribute__((ext_vector_type(8))) short short8;
typedef __attribute__((ext_vector_type(4))) float float4v;

#define BK 64

__device__ __forceinline__ float bf2f(unsigned short u) {
  union { unsigned int i; float f; } x;
  x.i = ((unsigned int)u) << 16;
  return x.f;
}
__device__ __forceinline__ unsigned short f2bf(float f) {
  union { float f; unsigned int i; } x;
  x.f = f;
  unsigned int r = x.i + 0x7fffu + ((x.i >> 16) & 1u);  // RNE
  return (unsigned short)(r >> 16);
}
__device__ __forceinline__ void load16(const void* g, void* l) {
  __builtin_amdgcn_global_load_lds(
      (__attribute__((address_space(1))) void*)g,
      (__attribute__((address_space(3))) void*)l, 16, 0, 0);
}
__device__ __forceinline__ short8 pack2(float4v lo, float4v hi) {
  short8 s;
  s[0] = (short)f2bf(lo[0]); s[1] = (short)f2bf(lo[1]);
  s[2] = (short)f2bf(lo[2]); s[3] = (short)f2bf(lo[3]);
  s[4] = (short)f2bf(hi[0]); s[5] = (short)f2bf(hi[1]);
  s[6] = (short)f2bf(hi[2]); s[7] = (short)f2bf(hi[3]);
  return s;
}
// a - b for two wave-uniform floats; avoids the gfx950 two-SGPR-source
// V_ADD_F32 constant-bus miscompile (R11) by forcing a through a VGPR.
__device__ __forceinline__ float vsub_uniform(float a, float b) {
  float av;
  asm("v_mov_b32 %0, %1" : "=v"(av) : "s"(a));
  return av - b;
}

// ---------------------------------------------------------------------------
// C = A(MxK row-major) * Bt(NxK bf16 row-major)^T, fused per-MODE epilogue.
// 64x64 tiles, 256 threads (4 waves 2x2, 32x32 out each, acc 2x2).
// ADT: 1 = A bf16 (global_load_lds, 2-phase counted-vmcnt pipeline,
//          epilogue preloads with vmcnt(4+P)),
//      0 = A f32 (reg-staged pipelined: 4x float4 prefetch + dbuf B).
// MODE: 0 INIT  u1=h@W1+b1: u1b=v, t1dst=tanh(v)
//       1 G1    u2=u1+.5dt(acc+c2): t1dst=tanh(u2), T:=aux+2*tanh
//       2 G2    u3=...: t1dst=tanh(u3), T+=2*tanh
//       3 G3    u4=u1+dt(acc+c2): T+=tanh(u4)
//       4 G4    u1'=u1+(dt/6)acc+dt*c2: u1b, t1dst=tanh, S (+)= (dt/6)*aux
//       5 ZFIN  z=h(aux)+acc+(t19-t0)*b2: t1dst=bf16(z)
//       6 WT    W21T[col*1024+row]=bf16(acc)   (builds W21^T)
//       7 OUT   outF=acc+bias
// ---------------------------------------------------------------------------
template <int MODE, int ADT>
__global__ __launch_bounds__(256, 4) void gemm_ode(
    const void* Av, const unsigned short* __restrict__ Bt,
    int N, int K,
    const float* __restrict__ bias, const float* __restrict__ tgrid,
    int step, int first,
    unsigned short* __restrict__ u1b,
    unsigned short* __restrict__ Tb,
    unsigned short* __restrict__ Sb,
    unsigned short* __restrict__ t1dst,
    const void* aux,
    const float* __restrict__ c2,
    float* __restrict__ outF) {
  __shared__ short8 AsV[2][512];  // 64 rows x 8 swizzled chunks x 16B
  __shared__ short8 BsV[2][512];

  const int t = threadIdx.x;
  int bx = blockIdx.x, by = blockIdx.y;
  // Bijective XCD stripe swizzle for (16,64): XCD x = lin&7 owns by in
  // [x*8, x*8+8). Working set/XCD: A 1MB + B 2MB = 3MB < 4MB L2.
  if (gridDim.x == 16 && gridDim.y == 64) {
    const int lin = bx + (by << 4);
    const int x = lin & 7, j = lin >> 3;  // j in 0..127
    bx = j & 15;
    by = (x << 3) | (j >> 4);
  }
  const int mBase = by * 64, nBase = bx * 64;
  const int wave = t >> 6, lane = t & 63;
  const int wr = wave >> 1, wc = wave & 1;
  const int q = lane >> 4, m16 = lane & 15;

  float4v acc[2][2];
#pragma unroll
  for (int r = 0; r < 2; ++r)
#pragma unroll
    for (int c = 0; c < 2; ++c) acc[r][c] = (float4v){0.f, 0.f, 0.f, 0.f};

  const int r0 = t >> 3;               // staging row 0..31 (also row+32)
  const int kcl = (t & 7) ^ (r0 & 7);  // swizzled k-chunk; (r0+32)&7==r0&7
  const unsigned short* aU = (const unsigned short*)Av + (size_t)(mBase + r0) * K + kcl * 8;
  const float* aF = (const float*)Av + (size_t)(mBase + r0) * K + kcl * 8;
  const unsigned short* bG = Bt + (size_t)(nBase + r0) * K + kcl * 8;

  const int colBase = nBase + wc * 32 + m16;
  const int rowBase = mBase + wr * 32 + q * 4;

  auto computeT = [&](int bufA, int bufB) {
#pragma unroll
    for (int kk = 0; kk < 2; ++kk) {
      const int kc = kk * 4 + q;
      short8 af[2], bfr[2];
#pragma unroll
      for (int r = 0; r < 2; ++r) {
        const int arow = wr * 32 + r * 16 + m16;
        af[r] = AsV[bufA][arow * 8 + (kc ^ (arow & 7))];
        const int brow = wc * 32 + r * 16 + m16;
        bfr[r] = BsV[bufB][brow * 8 + (kc ^ (brow & 7))];
      }
#pragma unroll
      for (int r = 0; r < 2; ++r)
#pragma unroll
        for (int c = 0; c < 2; ++c)
          acc[r][c] = __builtin_amdgcn_mfma_f32_16x16x32_bf16(af[r], bfr[c],
                                                              acc[r][c], 0, 0, 0);
    }
  };

  // epilogue preload storage (ADT1 modes; raw loads, converted in epilogue)
  unsigned short preA[2][2][4];  // u1b           (MODE 1..4)
  unsigned short preB[2][2][4];  // aux / Tb      (MODE 1..4)
  unsigned short preC[2][2][4];  // Sb            (MODE 4)
  float preF[2][2][4];           // aux f32 (h)   (MODE 5)
  float c2pre[2];                // c2 (1..4) / bias (5)

  if constexpr (ADT == 1) {
    auto stageT = [&](int buf, int k0) {
      load16(aU + k0, &AsV[buf][t]);
      load16(aU + (size_t)32 * K + k0, &AsV[buf][t + 256]);
      load16(bG + k0, &BsV[buf][t]);
      load16(bG + (size_t)32 * K + k0, &BsV[buf][t + 256]);
    };
    stageT(0, 0);
    int cur = 0;
#pragma unroll 1
    for (int k0 = BK; k0 < K - BK; k0 += BK) {  // tiles 1..14
      stageT(cur ^ 1, k0);
      asm volatile("s_waitcnt vmcnt(4)" ::: "memory");
      __builtin_amdgcn_sched_barrier(0);
      __builtin_amdgcn_s_barrier();
      __builtin_amdgcn_sched_barrier(0);
      computeT(cur, cur);
      asm volatile("s_waitcnt lgkmcnt(0)" ::: "memory");
      __builtin_amdgcn_sched_barrier(0);
      __builtin_amdgcn_s_barrier();
      __builtin_amdgcn_sched_barrier(0);
      cur ^= 1;
    }
    // ---- peeled last pipelined iteration: stage tile 15 + preloads ----
    stageT(cur ^ 1, K - BK);
    {
#pragma unroll
      for (int r = 0; r < 2; ++r)
#pragma unroll
        for (int c = 0; c < 2; ++c) {
          const int col = colBase + c * 16;
#pragma unroll
          for (int e = 0; e < 4; ++e) {
            const int row = rowBase + r * 16 + e;
            const size_t idx = (size_t)row * N + col;
            if constexpr (MODE >= 1 && MODE <= 4) preA[r][c][e] = u1b[idx];
            if constexpr (MODE == 1 || MODE == 4)
              preB[r][c][e] = ((const unsigned short*)aux)[idx];
            if constexpr (MODE == 2 || MODE == 3) preB[r][c][e] = Tb[idx];
            if constexpr (MODE == 4) preC[r][c][e] = Sb[idx];
            if constexpr (MODE == 5) preF[r][c][e] = ((const float*)aux)[idx];
          }
        }
#pragma unroll
      for (int c = 0; c < 2; ++c) {
        if constexpr (MODE >= 1 && MODE <= 4) c2pre[c] = c2[colBase + c * 16];
        if constexpr (MODE == 5) c2pre[c] = bias[colBase + c * 16];
      }
    }
    // Wait for tile 14 only: newest (4 + P) ops = tile15 + the P preloads
    // stay in flight. P exact per mode (scalar stride-2048 loads: unmergeable).
    if constexpr (MODE == 4)
      asm volatile("s_waitcnt vmcnt(54)" ::: "memory");  // 4 + 50
    else if constexpr (MODE == 5)
      asm volatile("s_waitcnt vmcnt(22)" ::: "memory");  // 4 + 18
    else
      asm volatile("s_waitcnt vmcnt(38)" ::: "memory");  // 4 + 34
    __builtin_amdgcn_sched_barrier(0);
    __builtin_amdgcn_s_barrier();
    __builtin_amdgcn_sched_barrier(0);
    computeT(cur, cur);
    asm volatile("s_waitcnt lgkmcnt(0)" ::: "memory");
    __builtin_amdgcn_sched_barrier(0);
    __builtin_amdgcn_s_barrier();
    __builtin_amdgcn_sched_barrier(0);
    cur ^= 1;
    // ---- tail: tile 15 (preloads also complete here, under the MFMAs) ----
    asm volatile("s_waitcnt vmcnt(0)" ::: "memory");
    __builtin_amdgcn_sched_barrier(0);
    __builtin_amdgcn_s_barrier();
    __builtin_amdgcn_sched_barrier(0);
    computeT(cur, cur);
  } else {
    // ---- ADT0: f32 A, reg-staged pipelined; Bs double-buffered ----
    struct RegsF { float4v a0, a1, a2, a3; };
    RegsF Ra, Rb;
    auto issueAF = [&](int k0, RegsF& R) {
      R.a0 = *(const float4v*)(aF + k0);
      R.a1 = *(const float4v*)(aF + k0 + 4);
      R.a2 = *(const float4v*)(aF + (size_t)32 * K + k0);
      R.a3 = *(const float4v*)(aF + (size_t)32 * K + k0 + 4);
    };
    auto issueBF = [&](int buf, int k0) {
      load16(bG + k0, &BsV[buf][t]);
      load16(bG + (size_t)32 * K + k0, &BsV[buf][t + 256]);
    };
    issueAF(0, Ra);
    issueBF(0, 0);
    int bufB = 0;
    auto stepI = [&](int k0, RegsF& Rc, RegsF& Rn) {
      if (k0 + BK < K) {
        issueAF(k0 + BK, Rn);
        issueBF(bufB ^ 1, k0 + BK);
        asm volatile("s_waitcnt vmcnt(6)" ::: "memory");  // current tile done
      } else {
        asm volatile("s_waitcnt vmcnt(0)" ::: "memory");
      }
      __builtin_amdgcn_sched_barrier(0);
      AsV[0][t] = pack2(Rc.a0, Rc.a1);
      AsV[0][t + 256] = pack2(Rc.a2, Rc.a3);
      asm volatile("s_waitcnt lgkmcnt(0)" ::: "memory");
      __builtin_amdgcn_sched_barrier(0);
      __builtin_amdgcn_s_barrier();
      __builtin_amdgcn_sched_barrier(0);
      computeT(0, bufB);
      asm volatile("s_waitcnt lgkmcnt(0)" ::: "memory");
      __builtin_amdgcn_sched_barrier(0);
      __builtin_amdgcn_s_barrier();
      __builtin_amdgcn_sched_barrier(0);
      bufB ^= 1;
    };
#pragma unroll 1
    for (int k0 = 0; k0 < K; k0 += 2 * BK) {
      stepI(k0, Ra, Rb);
      stepI(k0 + BK, Rb, Ra);
    }
  }

  // ---- fused epilogue ----
  float dtv = 0.f;
  if constexpr (MODE >= 1 && MODE <= 4) dtv = vsub_uniform(tgrid[step + 1], tgrid[step]);
  if constexpr (MODE == 5) dtv = vsub_uniform(tgrid[step], tgrid[0]);

#pragma unroll
  for (int r = 0; r < 2; ++r) {
#pragma unroll
    for (int c = 0; c < 2; ++c) {
      const int col = colBase + c * 16;
#pragma unroll
      for (int e = 0; e < 4; ++e) {
        const int row = rowBase + r * 16 + e;
        const size_t idx = (size_t)row * N + col;
        const float v = acc[r][c][e];
        if constexpr (MODE == 0) {
          const float u1 = v + bias[col];
          u1b[idx] = f2bf(u1);
          t1dst[idx] = f2bf(tanhf(u1));
        } else if constexpr (MODE == 1) {
          const float u2 = bf2f(preA[r][c][e]) + 0.5f * dtv * (v + c2pre[c]);
          const float th = tanhf(u2);
          t1dst[idx] = f2bf(th);
          Tb[idx] = f2bf(bf2f(preB[r][c][e]) + 2.f * th);
        } else if constexpr (MODE == 2) {
          const float u3 = bf2f(preA[r][c][e]) + 0.5f * dtv * (v + c2pre[c]);
          const float th = tanhf(u3);
          t1dst[idx] = f2bf(th);
          Tb[idx] = f2bf(bf2f(preB[r][c][e]) + 2.f * th);
        } else if constexpr (MODE == 3) {
          const float u4 = bf2f(preA[r][c][e]) + dtv * (v + c2pre[c]);
          Tb[idx] = f2bf(bf2f(preB[r][c][e]) + tanhf(u4));
        } else if constexpr (MODE == 4) {
          const float u1n = bf2f(preA[r][c][e]) + (dtv * (1.f / 6.f)) * v + dtv * c2pre[c];
          u1b[idx] = f2bf(u1n);
          t1dst[idx] = f2bf(tanhf(u1n));
          const float sOld = first ? 0.f : bf2f(preC[r][c][e]);
          Sb[idx] = f2bf(sOld + (dtv * (1.f / 6.f)) * bf2f(preB[r][c][e]));
        } else if constexpr (MODE == 5) {
          const float z = preF[r][c][e] + v + dtv * c2pre[c];
          t1dst[idx] = f2bf(z);
        } else if constexpr (MODE == 6) {
          t1dst[(size_t)col * 1024 + row] = f2bf(v);
        } else {  // MODE 7: out projection
          outF[idx] = v + bias[col];
        }
      }
    }
  }
}

// ---------------------------------------------------------------------------
// Fused gate + c_tilde dual GEMM, 64x64 tiles, 4 blocks/CU, pipelined (R15):
// A-side prefetched into registers one K-tile ahead, Bs double-buffered via
// global_load_lds; counted vmcnt(8). LDS 32 KB.
// ---------------------------------------------------------------------------
__global__ __launch_bounds__(256, 4) void gemm_fused(
    const float* __restrict__ x, const float* __restrict__ h,
    const unsigned short* __restrict__ zB,
    const unsigned short* __restrict__ WiT,  // 1024 x 1280 bf16
    const float* __restrict__ bi, const float* __restrict__ c_in,
    float* __restrict__ hnewF, float* __restrict__ cnewF) {
  __shared__ short8 AsG[512];
  __shared__ short8 AsC[512];
  __shared__ short8 Bs[2][512];

  const int t = threadIdx.x;
  int bx = blockIdx.x, by = blockIdx.y;
  {
    const int lin = bx + (by << 4);
    const int xc = lin & 7, j = lin >> 3;
    bx = j & 15;
    by = (xc << 3) | (j >> 4);
  }
  const int mBase = by * 64, nBase = bx * 64;
  const int wave = t >> 6, lane = t & 63;
  const int wr = wave >> 1, wc = wave & 1;
  const int q = lane >> 4, m16 = lane & 15;

  float4v accG[2][2], accC[2][2];
#pragma unroll
  for (int r = 0; r < 2; ++r)
#pragma unroll
    for (int c = 0; c < 2; ++c) {
      accG[r][c] = (float4v){0.f, 0.f, 0.f, 0.f};
      accC[r][c] = (float4v){0.f, 0.f, 0.f, 0.f};
    }

  const int r0 = t >> 3;
  const int kcl = (t & 7) ^ (r0 & 7);
  const int row0 = mBase + r0, row1 = row0 + 32;

  struct Regs { float4v a0, a1, a2, a3; short8 z0, z1; };
  Regs Ra, Rb;

  auto issueA = [&](int i, Regs& R) {
    const int k0 = i * 64;
    if (k0 < 256) {
      const float* g0 = x + (size_t)row0 * 256 + k0 + kcl * 8;
      const float* g1 = x + (size_t)row1 * 256 + k0 + kcl * 8;
      R.a0 = *(const float4v*)g0; R.a1 = *(const float4v*)(g0 + 4);
      R.a2 = *(const float4v*)g1; R.a3 = *(const float4v*)(g1 + 4);
      R.z0 = *(const short8*)(const void*)g0;  // dummy, keeps vmcnt uniform
      R.z1 = *(const short8*)(const void*)g1;
    } else {
      const size_t o0 = (size_t)row0 * 1024 + (k0 - 256) + kcl * 8;
      const size_t o1 = (size_t)row1 * 1024 + (k0 - 256) + kcl * 8;
      R.a0 = *(const float4v*)(h + o0); R.a1 = *(const float4v*)(h + o0 + 4);
      R.a2 = *(const float4v*)(h + o1); R.a3 = *(const float4v*)(h + o1 + 4);
      R.z0 = *(const short8*)(zB + o0);
      R.z1 = *(const short8*)(zB + o1);
    }
  };
  auto issueB = [&](int i, int buf) {
    const int k0 = i * 64;
    load16(WiT + (size_t)(nBase + r0) * 1280 + k0 + kcl * 8, &Bs[buf][t]);
    load16(WiT + (size_t)(nBase + r0 + 32) * 1280 + k0 + kcl * 8,
           &Bs[buf][t + 256]);
  };
  auto computeF = [&](int buf) {
#pragma unroll
    for (int kk = 0; kk < 2; ++kk) {
      const int kc = kk * 4 + q;
      short8 ag[2], ac[2], bfr[2];
#pragma unroll
      for (int r = 0; r < 2; ++r) {
        const int arow = wr * 32 + r * 16 + m16;
        ag[r] = AsG[arow * 8 + (kc ^ (arow & 7))];
        ac[r] = AsC[arow * 8 + (kc ^ (arow & 7))];
        const int brow = wc * 32 + r * 16 + m16;
        bfr[r] = Bs[buf][brow * 8 + (kc ^ (brow & 7))];
      }
#pragma unroll
      for (int r = 0; r < 2; ++r)
#pragma unroll
        for (int c = 0; c < 2; ++c) {
          accG[r][c] = __builtin_amdgcn_mfma_f32_16x16x32_bf16(ag[r], bfr[c],
                                                               accG[r][c], 0, 0, 0);
          accC[r][c] = __builtin_amdgcn_mfma_f32_16x16x32_bf16(ac[r], bfr[c],
                                                               accC[r][c], 0, 0, 0);
        }
    }
  };

  int buf = 0;
  auto stepF = [&](int i, Regs& Rc, Regs& Rn) {
    if (i + 1 < 20) {
      issueA(i + 1, Rn);
      issueB(i + 1, buf ^ 1);
      asm volatile("s_waitcnt vmcnt(8)" ::: "memory");  // tile i's 8 done
    } else {
      asm volatile("s_waitcnt vmcnt(0)" ::: "memory");
    }
    __builtin_amdgcn_sched_barrier(0);
    {
      const bool isX = (i * 64) < 256;
      const short8 s0 = pack2(Rc.a0, Rc.a1);
      const short8 s1 = pack2(Rc.a2, Rc.a3);
      AsG[t] = s0;
      AsG[t + 256] = s1;
      AsC[t] = isX ? s0 : Rc.z0;
      AsC[t + 256] = isX ? s1 : Rc.z1;
    }
    asm volatile("s_waitcnt lgkmcnt(0)" ::: "memory");
    __builtin_amdgcn_sched_barrier(0);
    __builtin_amdgcn_s_barrier();
    __builtin_amdgcn_sched_barrier(0);
    computeF(buf);
    asm volatile("s_waitcnt lgkmcnt(0)" ::: "memory");
    __builtin_amdgcn_sched_barrier(0);
    __builtin_amdgcn_s_barrier();  // all waves done reading As/Bs[buf]
    __builtin_amdgcn_sched_barrier(0);
    buf ^= 1;
  };

  issueA(0, Ra);
  issueB(0, 0);
#pragma unroll 1
  for (int ii = 0; ii < 20; ii += 2) {
    stepF(ii, Ra, Rb);
    stepF(ii + 1, Rb, Ra);
  }

  const int colBase = nBase + wc * 32 + m16;
  const int rowBase = mBase + wr * 32 + q * 4;
#pragma unroll
  for (int r = 0; r < 2; ++r) {
#pragma unroll
    for (int c = 0; c < 2; ++c) {
      const int col = colBase + c * 16;
      const float bv = bi[col];
#pragma unroll
      for (int e = 0; e < 4; ++e) {
        const int row = rowBase + r * 16 + e;
        const size_t idx = (size_t)row * 1024 + col;
        const float g = 1.f / (1.f + expf(-(accG[r][c][e] + bv)));
        const float ct = 1.f / (1.f + expf(-(accC[r][c][e] + bv)));
        const float cn = g * (c_in[idx] + ct);
        const float hn = g * tanhf(cn);
        hnewF[idx] = hn;
        cnewF[idx] = cn;
      }
    }
  }
}

// ---------------------------------------------------------------------------
// prep_all: 4 weight transposes (f32 -> bf16 NxK) + c2 = b2@W1, one dispatch.
// blocks [0,1024) W1T | [1024,2048) W2T | [2048,3328) WiT | [3328,3584) WoT |
// [3584,3600) c2 (16 blocks x 64 n, 4-way K-split, deterministic reduce).
// ---------------------------------------------------------------------------
__global__ __launch_bounds__(256) void prep_all(
    const float* __restrict__ W1, const float* __restrict__ W2,
    const float* __restrict__ Wi, const float* __restrict__ Wo,
    const float* __restrict__ b2,
    unsigned short* __restrict__ W1T, unsigned short* __restrict__ W2T,
    unsigned short* __restrict__ WiT, unsigned short* __restrict__ WoT,
    float* __restrict__ c2v) {
  const int bid = blockIdx.x;
  const int t = threadIdx.x;
  if (bid < 3584) {
    const float* in;
    unsigned short* out;
    int R, C, bx, by;
    if (bid < 1024) {
      in = W1; out = W1T; R = 1024; C = 1024;
      bx = bid & 31; by = bid >> 5;
    } else if (bid < 2048) {
      in = W2; out = W2T; R = 1024; C = 1024;
      const int b = bid - 1024; bx = b & 31; by = b >> 5;
    } else if (bid < 3328) {
      in = Wi; out = WiT; R = 1280; C = 1024;
      const int b = bid - 2048; bx = b & 31; by = b >> 5;
    } else {
      in = Wo; out = WoT; R = 1024; C = 256;
      const int b = bid - 3328; bx = b & 7; by = b >> 3;
    }
    __shared__ float tile[32][33];
    const int c0 = bx * 32, r0 = by * 32;
    const int tx = t & 31, ty = t >> 5;  // 32 x 8
#pragma unroll
    for (int i = 0; i < 32; i += 8)
      tile[ty + i][tx] = in[(size_t)(r0 + ty + i) * C + c0 + tx];
    __syncthreads();
#pragma unroll
    for (int i = 0; i < 32; i += 8)
      out[(size_t)(c0 + ty + i) * R + r0 + tx] = f2bf(tile[tx][ty + i]);
  } else {
    __shared__ float part[4][64];
    const int b = bid - 3584;            // 0..15
    const int nl = t & 63, kq = t >> 6;  // n-local, k-quarter
    const int n = b * 64 + nl;
    float a = 0.f;
    for (int k = kq * 256; k < kq * 256 + 256; ++k)
      a += b2[k] * W1[(size_t)k * 1024 + n];
    part[kq][nl] = a;
    __syncthreads();
    if (kq == 0)
      c2v[n] = ((part[0][nl] + part[1][nl]) + part[2][nl]) + part[3][nl];
  }
}

extern "C" void kernel_launch(void* const* d_in, const int* in_sizes, int n_in,
                              void* d_out, int out_size, void* d_ws, size_t ws_size,
                              hipStream_t stream) {
  const float* x  = (const float*)d_in[0];   // 4096x256
  const float* h  = (const float*)d_in[1];   // 4096x1024
  const float* c  = (const float*)d_in[2];   // 4096x1024
  const float* t  = (const float*)d_in[3];   // 20
  const float* Wi = (const float*)d_in[4];   // 1280x1024
  const float* bi = (const float*)d_in[5];   // 1024
  const float* Wo = (const float*)d_in[6];   // 1024x256
  const float* bo = (const float*)d_in[7];   // 256
  const float* W1 = (const float*)d_in[8];   // 1024x1024
  const float* b1 = (const float*)d_in[9];   // 1024
  const float* W2 = (const float*)d_in[10];  // 1024x1024
  const float* b2 = (const float*)d_in[11];  // 1024

  const size_t MB = 1ull << 20;
  char* ws = (char*)d_ws;
  unsigned short* W21T = (unsigned short*)(ws);                      // [0,2M)
  unsigned short* W2T  = (unsigned short*)(ws + 2 * MB);             // [2,4M)
  unsigned short* WiT  = (unsigned short*)(ws + 4 * MB);             // [4,6.5M)
  unsigned short* WoT  = (unsigned short*)(ws + 6 * MB + 512 * 1024);// [6.5,7M)
  unsigned short* P0   = (unsigned short*)(ws + 7 * MB);             // [7,15M)

  // d_out overlays (all dead before the final output writes)
  float*          outF  = (float*)d_out;
  float*          hnewF = outF + 1048576;                            // [4,20M)
  float*          cnewF = outF + 5242880;                            // [20,36M)
  unsigned short* u1b   = (unsigned short*)d_out;                    // [0,8M)
  unsigned short* Tb    = (unsigned short*)((char*)d_out + 8 * MB);  // [8,16M)
  unsigned short* P1    = (unsigned short*)((char*)d_out + 16 * MB); // [16,24M)
  unsigned short* Sb    = (unsigned short*)((char*)d_out + 24 * MB); // [24,32M)
  unsigned short* W1T   = (unsigned short*)((char*)d_out + 32 * MB); // [32,34M)
  float*          c2v   = (float*)((char*)d_out + 34 * MB);          // 4 KB

  const dim3 blk(256), g(16, 64);

  // weight prep (one dispatch: 4 transposes + c2)
  prep_all<<<3600, blk, 0, stream>>>(W1, W2, Wi, Wo, b2,
                                     W1T, W2T, WiT, WoT, c2v);
  // W21T = (W2@W1)^T   (pipelined f32-A path)
  gemm_ode<6, 0><<<dim3(16, 16), blk, 0, stream>>>(
      W2, W1T, 1024, 1024, b1, t, 0, 0,
      nullptr, nullptr, nullptr, W21T, nullptr, nullptr, nullptr);
  // u1 = h@W1 + b1 ; t1_1 = tanh(u1) -> P0   (pipelined f32-A path)
  gemm_ode<0, 0><<<g, blk, 0, stream>>>(
      h, W1T, 1024, 1024, b1, t, 0, 0,
      u1b, nullptr, nullptr, P0, nullptr, nullptr, nullptr);

  // RK4: 19 steps x 4 single GEMMs (all vs W21T)
  for (int s = 0; s < 19; ++s) {
    gemm_ode<1, 1><<<g, blk, 0, stream>>>(
        P0, W21T, 1024, 1024, b1, t, s, 0,
        u1b, Tb, nullptr, P1, P0, c2v, nullptr);
    gemm_ode<2, 1><<<g, blk, 0, stream>>>(
        P1, W21T, 1024, 1024, b1, t, s, 0,
        u1b, Tb, nullptr, P0, nullptr, c2v, nullptr);
    gemm_ode<3, 1><<<g, blk, 0, stream>>>(
        P0, W21T, 1024, 1024, b1, t, s, 0,
        u1b, Tb, nullptr, nullptr, nullptr, c2v, nullptr);
    gemm_ode<4, 1><<<g, blk, 0, stream>>>(
        Tb, W21T, 1024, 1024, b1, t, s, (s == 0) ? 1 : 0,
        u1b, nullptr, Sb, P0, Tb, c2v, nullptr);
  }

  // z = h_ode = h + S@W2 + (t19-t0)*b2  -> bf16 into P0
  gemm_ode<5, 1><<<g, blk, 0, stream>>>(
      Sb, W2T, 1024, 1024, b2, t, 19, 0,
      nullptr, nullptr, nullptr, P0, h, nullptr, nullptr);

  // fused gate + c_tilde -> h_new, c_new (f32)
  gemm_fused<<<g, blk, 0, stream>>>(x, h, P0, WiT, bi, c, hnewF, cnewF);

  // out = h_new(f32) @ Wo + bo   (pipelined f32-A path)
  gemm_ode<7, 0><<<dim3(4, 64), blk, 0, stream>>>(
      hnewF, WoT, 256, 1024, bo, t, 0, 0,
      nullptr, nullptr, nullptr, nullptr, nullptr, nullptr, outF);
}